// Round 2
// baseline (948.263 us; speedup 1.0000x reference)
//
#include <hip/hip_runtime.h>
#include <hip/hip_bf16.h>

#define NN 4096
#define NITER 8
#define NSWEEP 9

// workspace float layout
#define OFF_STS  64               // StS[4096]
#define OFF_QRHO (OFF_STS + NN)   // q_i + rho
#define OFF_DINV (OFF_QRHO + NN)  // 1/diag(A)
#define OFF_X    (OFF_DINV + NN)
#define OFF_R    (OFF_X + NN)
#define OFF_P    (OFF_R + NN)
#define OFF_Y    (OFF_P + NN)
// wf[0] = pTy accumulator, wf[1] = rz accumulator

// ---------------- StS = S^T S (64x64) ----------------
__global__ void k_sts(const float* __restrict__ S, float* __restrict__ wf){
    int t = blockIdx.x * 256 + threadIdx.x;   // 4096 threads
    int r = t >> 6, c = t & 63;
    float acc = 0.f;
    for(int h = 0; h < 64; ++h)
        acc += S[h*64 + r] * S[h*64 + c];
    wf[OFF_STS + t] = acc;
}

// ---------------- prep: b, diag, CG init ----------------
__global__ void k_prep(const float* __restrict__ inp, const float* __restrict__ L,
                       const int*  __restrict__ mask, const float* __restrict__ D,
                       const float* __restrict__ thP,
                       const float* __restrict__ l1p, const float* __restrict__ l2p,
                       const float* __restrict__ rhop,
                       float* __restrict__ wf){
    int i = blockIdx.x * 256 + threadIdx.x;   // 4096 threads
    float rho = rhop[0], l1 = l1p[0], l2 = l2p[0];
    float q = (mask[i] != 0) ? 1.f : 0.f;
    float bi = rho * (L[i] - thP[i]) + q * inp[i];
    int u = i & 63;
    float diag = q + rho + l2 * wf[OFF_STS + u*64 + u] + l1 * D[(size_t)i*4096 + i];
    float dinv = 1.f / diag;
    wf[OFF_QRHO + i] = q + rho;
    wf[OFF_DINV + i] = dinv;
    wf[OFF_X + i]    = 0.f;
    wf[OFF_R + i]    = bi;
    float z = bi * dinv;
    wf[OFF_P + i]    = z;
    // reduce b*z -> rz
    float part = bi * z;
    for(int m = 32; m >= 1; m >>= 1) part += __shfl_xor(part, m, 64);
    __shared__ float red[4];
    int wave = threadIdx.x >> 6, lane = threadIdx.x & 63;
    if(lane == 0) red[wave] = part;
    __syncthreads();
    if(threadIdx.x == 0) atomicAdd(&wf[1], red[0] + red[1] + red[2] + red[3]);
}

// ---------------- y = A p, accumulate p^T y ----------------
__launch_bounds__(256)
__global__ void k_matvec(const float* __restrict__ D,
                         const float* __restrict__ l1p, const float* __restrict__ l2p,
                         float* __restrict__ wf){
    __shared__ float psh[NN];
    __shared__ float red[4];
    const float* p    = wf + OFF_P;
    const float* qrho = wf + OFF_QRHO;
    const float* StS  = wf + OFF_STS;
    float* y          = wf + OFF_Y;
    int tid = threadIdx.x;
    // stage p into LDS (16 KB)
    const float4* p4 = (const float4*)p;
    float4* psh4 = (float4*)psh;
    for(int k = 0; k < 4; ++k) psh4[tid + k*256] = p4[tid + k*256];
    __syncthreads();

    float l1 = l1p[0], l2 = l2p[0];
    int wave = tid >> 6, lane = tid & 63;
    int row = blockIdx.x * 4 + wave;          // 1024 blocks -> 4096 rows
    int h = row >> 6, u = row & 63;

    const float* Drow = D + (size_t)row * NN;
    float dacc = 0.f;
    for(int j = 0; j < 16; ++j){
        int c0 = j*256 + lane*4;              // lane reads 4 floats = 16B, wave reads 1KB contig
        float4 dv = *(const float4*)(Drow + c0);
        float4 pa = *(const float4*)(psh + c0);
        dacc += dv.x*pa.x + dv.y*pa.y + dv.z*pa.z + dv.w*pa.w;
    }
    // S_tilda part: (StS @ p[h*64 : h*64+64])[u]
    float sacc = StS[u*64 + lane] * psh[h*64 + lane];
    float val = l1 * dacc + l2 * sacc;
    for(int m = 32; m >= 1; m >>= 1) val += __shfl_xor(val, m, 64);
    if(lane == 0){
        float yi = val + qrho[row] * psh[row];
        y[row] = yi;
        red[wave] = yi * psh[row];
    }
    __syncthreads();
    if(tid == 0) atomicAdd(&wf[0], red[0] + red[1] + red[2] + red[3]);
}

// ---------------- CG scalar/vector update (one block) ----------------
__launch_bounds__(1024)
__global__ void k_cgupd(float* __restrict__ wf){
    __shared__ float lds[16];
    int tid = threadIdx.x;
    float pTy = wf[0], rz = wf[1];
    float alpha = rz / pTy;
    float* x    = wf + OFF_X;
    float* r    = wf + OFF_R;
    float* p    = wf + OFF_P;
    const float* y    = wf + OFF_Y;
    const float* dinv = wf + OFF_DINV;

    float zi[4], pi[4];
    float part = 0.f;
    for(int k = 0; k < 4; ++k){
        int i = tid + k*1024;
        float pv = p[i]; pi[k] = pv;
        x[i] += alpha * pv;
        float rv = r[i] - alpha * y[i];
        r[i] = rv;
        float z = rv * dinv[i];
        zi[k] = z;
        part += rv * z;
    }
    for(int m = 32; m >= 1; m >>= 1) part += __shfl_xor(part, m, 64);
    int wave = tid >> 6, lane = tid & 63;
    if(lane == 0) lds[wave] = part;
    __syncthreads();
    float rznew = 0.f;
    for(int w = 0; w < 16; ++w) rznew += lds[w];
    float beta = rznew / rz;
    for(int k = 0; k < 4; ++k){
        int i = tid + k*1024;
        p[i] = zi[k] + beta * pi[k];
    }
    if(tid == 0){ wf[1] = rznew; wf[0] = 0.f; }
}

// ---------------- SVT via one-sided Hestenes-Jacobi + epilogue ----------------
__launch_bounds__(1024)
__global__ void k_svt(const float* __restrict__ thP, const float* __restrict__ vp,
                      const float* __restrict__ netap,
                      const float* __restrict__ wf, float* __restrict__ out){
    __shared__ float W[NN];   // column-major: W[c*64+r]
    __shared__ float V[NN];
    __shared__ float s2[64], coef[64];
    __shared__ float smaxsh;
    int tid = threadIdx.x;
    const float* x = wf + OFF_X;

    for(int k = 0; k < 4; ++k){
        int n = tid + k*1024;
        int r = n >> 6, c = n & 63;
        W[c*64 + r] = x[n] + thP[n];
        V[n] = (r == c) ? 1.f : 0.f;   // identity (symmetric, layout-agnostic)
    }
    __syncthreads();

    int pr = tid >> 5, lane = tid & 31;   // 32 pairs x 32 lanes
    for(int sweep = 0; sweep < NSWEEP; ++sweep){
        for(int rnd = 0; rnd < 63; ++rnd){
            int cp, cq;
            if(pr == 0){ cp = 63; cq = rnd; }
            else { cp = (rnd + pr) % 63; cq = (rnd + 63 - pr) % 63; }
            float* Wp = W + cp*64; float* Wq = W + cq*64;
            float2 wp = *(float2*)(Wp + lane*2);
            float2 wq = *(float2*)(Wq + lane*2);
            float aa = wp.x*wp.x + wp.y*wp.y;
            float bb = wq.x*wq.x + wq.y*wq.y;
            float cc = wp.x*wq.x + wp.y*wq.y;
            for(int m = 16; m >= 1; m >>= 1){
                aa += __shfl_xor(aa, m, 32);
                bb += __shfl_xor(bb, m, 32);
                cc += __shfl_xor(cc, m, 32);
            }
            if(fabsf(cc) > 1e-30f){
                float zeta = (bb - aa) / (2.f * cc);
                float t = copysignf(1.f / (fabsf(zeta) + sqrtf(1.f + zeta*zeta)), zeta);
                float cs = rsqrtf(1.f + t*t);
                float sn = t * cs;
                float2 nwp, nwq;
                nwp.x = cs*wp.x - sn*wq.x;  nwp.y = cs*wp.y - sn*wq.y;
                nwq.x = sn*wp.x + cs*wq.x;  nwq.y = sn*wp.y + cs*wq.y;
                *(float2*)(Wp + lane*2) = nwp;
                *(float2*)(Wq + lane*2) = nwq;
                float* Vp = V + cp*64; float* Vq = V + cq*64;
                float2 vp2 = *(float2*)(Vp + lane*2);
                float2 vq2 = *(float2*)(Vq + lane*2);
                float2 nvp, nvq;
                nvp.x = cs*vp2.x - sn*vq2.x;  nvp.y = cs*vp2.y - sn*vq2.y;
                nvq.x = sn*vp2.x + cs*vq2.x;  nvq.y = sn*vp2.y + cs*vq2.y;
                *(float2*)(Vp + lane*2) = nvp;
                *(float2*)(Vq + lane*2) = nvq;
            }
            __syncthreads();
        }
    }

    // column norms (group pr handles cols 2pr, 2pr+1)
    {
        int c0 = 2*pr, c1 = 2*pr + 1;
        float2 w0 = *(float2*)(W + c0*64 + lane*2);
        float2 w1 = *(float2*)(W + c1*64 + lane*2);
        float aa = w0.x*w0.x + w0.y*w0.y;
        float bb = w1.x*w1.x + w1.y*w1.y;
        for(int m = 16; m >= 1; m >>= 1){
            aa += __shfl_xor(aa, m, 32);
            bb += __shfl_xor(bb, m, 32);
        }
        if(lane == 0){ s2[c0] = aa; s2[c1] = bb; }
    }
    __syncthreads();
    if(tid == 0){
        float sm = 0.f;
        for(int c = 0; c < 64; ++c) sm = fmaxf(sm, s2[c]);
        smaxsh = sqrtf(sm);
    }
    __syncthreads();
    if(tid < 64){
        float s = sqrtf(s2[tid]);
        float v = vp[0];
        float tau = 0.4f / (1.f + expf(-v));        // sigmoid(v) * COEF_GAMMA
        float thr = s - tau * smaxsh;
        coef[tid] = (thr > 0.f && s > 1e-20f) ? thr / s : 0.f;
    }
    __syncthreads();

    float neta = netap[0];
    for(int k = 0; k < 4; ++k){
        int n = tid + k*1024;
        int i = n >> 6, j = n & 63;
        float acc = 0.f;
        for(int kk = 0; kk < 64; ++kk){
            float ck = coef[kk];
            if(ck != 0.f) acc += ck * W[kk*64 + i] * V[kk*64 + j];
        }
        out[n] = acc;                                  // Ltmp
        float pv = thP[n] + neta * (x[n] - acc);
        out[NN + n] = pv;                              // Ptmp
    }
}

extern "C" void kernel_launch(void* const* d_in, const int* in_sizes, int n_in,
                              void* d_out, int out_size, void* d_ws, size_t ws_size,
                              hipStream_t stream){
    const float* inp  = (const float*)d_in[0];
    const float* L    = (const float*)d_in[1];
    const int*   mask = (const int*)  d_in[2];
    const float* D    = (const float*)d_in[3];
    const float* thP  = (const float*)d_in[4];
    const float* vS   = (const float*)d_in[5];
    const float* neta = (const float*)d_in[6];
    const float* l1   = (const float*)d_in[7];
    const float* l2   = (const float*)d_in[8];
    const float* rho  = (const float*)d_in[9];
    const float* S    = (const float*)d_in[10];
    float* wf = (float*)d_ws;
    float* out = (float*)d_out;

    hipMemsetAsync(d_ws, 0, 64 * sizeof(float), stream);   // zero pTy/rz accumulators
    k_sts <<<16, 256, 0, stream>>>(S, wf);
    k_prep<<<16, 256, 0, stream>>>(inp, L, mask, D, thP, l1, l2, rho, wf);
    for(int it = 0; it < NITER; ++it){
        k_matvec<<<1024, 256, 0, stream>>>(D, l1, l2, wf);
        k_cgupd <<<1, 1024, 0, stream>>>(wf);
    }
    k_svt<<<1, 1024, 0, stream>>>(thP, vS, neta, wf, out);
}

// Round 3
// 527.164 us; speedup vs baseline: 1.7988x; 1.7988x over previous
//
#include <hip/hip_runtime.h>
#include <hip/hip_bf16.h>

#define NN 4096
#define NITER 8
#define NSWEEP 6

// workspace float layout
#define OFF_STS  64               // StS[4096]
#define OFF_QRHO (OFF_STS + NN)   // q_i + rho
#define OFF_DINV (OFF_QRHO + NN)  // 1/diag(A)
#define OFF_X    (OFF_DINV + NN)
#define OFF_R    (OFF_X + NN)
#define OFF_P    (OFF_R + NN)
#define OFF_Y    (OFF_P + NN)
// wf[0] = pTy accumulator, wf[1] = rz accumulator
#define DH_OFF_BYTES 131072              // bf16 copy of D at 128KB into ws
#define WS_NEED_BF16 (DH_OFF_BYTES + (size_t)NN * NN * 2)

typedef unsigned int uint;
__device__ inline float lo2f(uint w){ return __uint_as_float(w << 16); }
__device__ inline float hi2f(uint w){ return __uint_as_float(w & 0xffff0000u); }
__device__ inline unsigned short f2b(float f){
    uint u = __float_as_uint(f);
    return (unsigned short)((u + 0x7FFFu + ((u >> 16) & 1u)) >> 16);   // RNE
}

// ---------------- StS = S^T S (64x64) ----------------
__global__ void k_sts(const float* __restrict__ S, float* __restrict__ wf){
    int t = blockIdx.x * 256 + threadIdx.x;   // 4096 threads
    int r = t >> 6, c = t & 63;
    float acc = 0.f;
    for(int h = 0; h < 64; ++h)
        acc += S[h*64 + r] * S[h*64 + c];
    wf[OFF_STS + t] = acc;
}

// ---------------- D (fp32) -> Dh (bf16) ----------------
__global__ void k_conv(const float* __restrict__ D, unsigned short* __restrict__ Dh){
    int t = blockIdx.x * 256 + threadIdx.x;      // 8192 blocks
    size_t base = (size_t)t * 8;
    float4 a = *(const float4*)(D + base);
    float4 b = *(const float4*)(D + base + 4);
    uint4 o;
    o.x = (uint)f2b(a.x) | ((uint)f2b(a.y) << 16);
    o.y = (uint)f2b(a.z) | ((uint)f2b(a.w) << 16);
    o.z = (uint)f2b(b.x) | ((uint)f2b(b.y) << 16);
    o.w = (uint)f2b(b.z) | ((uint)f2b(b.w) << 16);
    *(uint4*)(Dh + base) = o;
}

// ---------------- prep: b, diag, CG init ----------------
__global__ void k_prep(const float* __restrict__ inp, const float* __restrict__ L,
                       const int*  __restrict__ mask, const float* __restrict__ D,
                       const float* __restrict__ thP,
                       const float* __restrict__ l1p, const float* __restrict__ l2p,
                       const float* __restrict__ rhop,
                       float* __restrict__ wf){
    int i = blockIdx.x * 256 + threadIdx.x;   // 4096 threads
    float rho = rhop[0], l1 = l1p[0], l2 = l2p[0];
    float q = (mask[i] != 0) ? 1.f : 0.f;
    float bi = rho * (L[i] - thP[i]) + q * inp[i];
    int u = i & 63;
    float diag = q + rho + l2 * wf[OFF_STS + u*64 + u] + l1 * D[(size_t)i*4096 + i];
    float dinv = 1.f / diag;
    wf[OFF_QRHO + i] = q + rho;
    wf[OFF_DINV + i] = dinv;
    wf[OFF_X + i]    = 0.f;
    wf[OFF_R + i]    = bi;
    float z = bi * dinv;
    wf[OFF_P + i]    = z;
    float part = bi * z;
    for(int m = 32; m >= 1; m >>= 1) part += __shfl_xor(part, m, 64);
    __shared__ float red[4];
    int wave = threadIdx.x >> 6, lane = threadIdx.x & 63;
    if(lane == 0) red[wave] = part;
    __syncthreads();
    if(threadIdx.x == 0) atomicAdd(&wf[1], red[0] + red[1] + red[2] + red[3]);
}

// ---------------- y = A p (bf16 D), accumulate p^T y ----------------
__launch_bounds__(256)
__global__ void k_matvec_h(const unsigned short* __restrict__ Dh,
                           const float* __restrict__ l1p, const float* __restrict__ l2p,
                           float* __restrict__ wf){
    __shared__ float psh[NN];
    __shared__ float red[4];
    const float* p    = wf + OFF_P;
    const float* qrho = wf + OFF_QRHO;
    const float* StS  = wf + OFF_STS;
    float* y          = wf + OFF_Y;
    int tid = threadIdx.x;
    const float4* p4 = (const float4*)p;
    float4* psh4 = (float4*)psh;
    for(int k = 0; k < 4; ++k) psh4[tid + k*256] = p4[tid + k*256];
    __syncthreads();

    float l1 = l1p[0], l2 = l2p[0];
    int wave = tid >> 6, lane = tid & 63;
    int row = blockIdx.x * 4 + wave;
    int h = row >> 6, u = row & 63;

    const unsigned short* Drow = Dh + (size_t)row * NN;
    float dacc = 0.f;
    for(int j = 0; j < 8; ++j){
        int c0 = j*512 + lane*8;
        uint4 dv = *(const uint4*)(Drow + c0);
        float4 pa = *(const float4*)(psh + c0);
        float4 pb = *(const float4*)(psh + c0 + 4);
        dacc += lo2f(dv.x)*pa.x + hi2f(dv.x)*pa.y
              + lo2f(dv.y)*pa.z + hi2f(dv.y)*pa.w
              + lo2f(dv.z)*pb.x + hi2f(dv.z)*pb.y
              + lo2f(dv.w)*pb.z + hi2f(dv.w)*pb.w;
    }
    float sacc = StS[u*64 + lane] * psh[h*64 + lane];
    float val = l1 * dacc + l2 * sacc;
    for(int m = 32; m >= 1; m >>= 1) val += __shfl_xor(val, m, 64);
    if(lane == 0){
        float yi = val + qrho[row] * psh[row];
        y[row] = yi;
        red[wave] = yi * psh[row];
    }
    __syncthreads();
    if(tid == 0) atomicAdd(&wf[0], red[0] + red[1] + red[2] + red[3]);
}

// ---------------- y = A p (fp32 D fallback) ----------------
__launch_bounds__(256)
__global__ void k_matvec_f(const float* __restrict__ D,
                           const float* __restrict__ l1p, const float* __restrict__ l2p,
                           float* __restrict__ wf){
    __shared__ float psh[NN];
    __shared__ float red[4];
    const float* p    = wf + OFF_P;
    const float* qrho = wf + OFF_QRHO;
    const float* StS  = wf + OFF_STS;
    float* y          = wf + OFF_Y;
    int tid = threadIdx.x;
    const float4* p4 = (const float4*)p;
    float4* psh4 = (float4*)psh;
    for(int k = 0; k < 4; ++k) psh4[tid + k*256] = p4[tid + k*256];
    __syncthreads();

    float l1 = l1p[0], l2 = l2p[0];
    int wave = tid >> 6, lane = tid & 63;
    int row = blockIdx.x * 4 + wave;
    int h = row >> 6, u = row & 63;

    const float* Drow = D + (size_t)row * NN;
    float dacc = 0.f;
    for(int j = 0; j < 16; ++j){
        int c0 = j*256 + lane*4;
        float4 dv = *(const float4*)(Drow + c0);
        float4 pa = *(const float4*)(psh + c0);
        dacc += dv.x*pa.x + dv.y*pa.y + dv.z*pa.z + dv.w*pa.w;
    }
    float sacc = StS[u*64 + lane] * psh[h*64 + lane];
    float val = l1 * dacc + l2 * sacc;
    for(int m = 32; m >= 1; m >>= 1) val += __shfl_xor(val, m, 64);
    if(lane == 0){
        float yi = val + qrho[row] * psh[row];
        y[row] = yi;
        red[wave] = yi * psh[row];
    }
    __syncthreads();
    if(tid == 0) atomicAdd(&wf[0], red[0] + red[1] + red[2] + red[3]);
}

// ---------------- CG scalar/vector update (one block) ----------------
__launch_bounds__(1024)
__global__ void k_cgupd(float* __restrict__ wf){
    __shared__ float lds[16];
    int tid = threadIdx.x;
    float pTy = wf[0], rz = wf[1];
    float alpha = rz / pTy;
    float* x    = wf + OFF_X;
    float* r    = wf + OFF_R;
    float* p    = wf + OFF_P;
    const float* y    = wf + OFF_Y;
    const float* dinv = wf + OFF_DINV;

    float zi[4], pi[4];
    float part = 0.f;
    for(int k = 0; k < 4; ++k){
        int i = tid + k*1024;
        float pv = p[i]; pi[k] = pv;
        x[i] += alpha * pv;
        float rv = r[i] - alpha * y[i];
        r[i] = rv;
        float z = rv * dinv[i];
        zi[k] = z;
        part += rv * z;
    }
    for(int m = 32; m >= 1; m >>= 1) part += __shfl_xor(part, m, 64);
    int wave = tid >> 6, lane = tid & 63;
    if(lane == 0) lds[wave] = part;
    __syncthreads();
    float rznew = 0.f;
    for(int w = 0; w < 16; ++w) rznew += lds[w];
    float beta = rznew / rz;
    for(int k = 0; k < 4; ++k){
        int i = tid + k*1024;
        p[i] = zi[k] + beta * pi[k];
    }
    if(tid == 0){ wf[1] = rznew; wf[0] = 0.f; }
}

// ---------------- SVT: one-sided Jacobi (no V), b128 LDS, 256 thr ----------------
// After convergence W = U diag(s). Ltmp = W diag(relu(s-thr)/s^3) (W^T X).
__launch_bounds__(256)
__global__ void k_svt(const float* __restrict__ thP, const float* __restrict__ vp,
                      const float* __restrict__ netap,
                      const float* __restrict__ wf, float* __restrict__ out){
    __shared__ float Wc[NN];    // col-major: Wc[c*64+r]
    __shared__ float Xsh[NN];   // row-major: Xsh[r*64+j]
    __shared__ float Tsh[NN];   // T'[k*64+j]
    __shared__ float s2[64], coef3[64];
    __shared__ float smax_sh;
    int tid = threadIdx.x;
    const float* x = wf + OFF_X;

    // stage X = x + thP (row-major) and W = X (col-major)
    for(int k = 0; k < 16; ++k){
        int n = tid + k*256;
        int r = n >> 6, c = n & 63;
        float v = x[n] + thP[n];
        Xsh[n] = v;
        Wc[c*64 + r] = v;
    }
    __syncthreads();

    int g  = tid >> 3;      // pair group 0..31
    int sl = tid & 7;       // sub-lane: rows 8*sl .. 8*sl+7
    for(int sweep = 0; sweep < NSWEEP; ++sweep){
      for(int rnd = 0; rnd < 63; ++rnd){
        int p, q;
        if(g == 0){ p = 63; q = rnd; }
        else { p = (rnd + g) % 63; q = (rnd + 63 - g) % 63; }
        float* Wp = Wc + p*64 + sl*8;
        float* Wq = Wc + q*64 + sl*8;
        float4 wp0 = *(float4*)(Wp);
        float4 wp1 = *(float4*)(Wp + 4);
        float4 wq0 = *(float4*)(Wq);
        float4 wq1 = *(float4*)(Wq + 4);
        float aa = wp0.x*wp0.x + wp0.y*wp0.y + wp0.z*wp0.z + wp0.w*wp0.w
                 + wp1.x*wp1.x + wp1.y*wp1.y + wp1.z*wp1.z + wp1.w*wp1.w;
        float bb = wq0.x*wq0.x + wq0.y*wq0.y + wq0.z*wq0.z + wq0.w*wq0.w
                 + wq1.x*wq1.x + wq1.y*wq1.y + wq1.z*wq1.z + wq1.w*wq1.w;
        float cc = wp0.x*wq0.x + wp0.y*wq0.y + wp0.z*wq0.z + wp0.w*wq0.w
                 + wp1.x*wq1.x + wp1.y*wq1.y + wp1.z*wq1.z + wp1.w*wq1.w;
        aa += __shfl_xor(aa, 1, 8); bb += __shfl_xor(bb, 1, 8); cc += __shfl_xor(cc, 1, 8);
        aa += __shfl_xor(aa, 2, 8); bb += __shfl_xor(bb, 2, 8); cc += __shfl_xor(cc, 2, 8);
        aa += __shfl_xor(aa, 4, 8); bb += __shfl_xor(bb, 4, 8); cc += __shfl_xor(cc, 4, 8);
        if(fabsf(cc) > 1e-30f){
            float zeta = (bb - aa) / (2.f * cc);
            float t = copysignf(1.f / (fabsf(zeta) + sqrtf(1.f + zeta*zeta)), zeta);
            float cs = rsqrtf(1.f + t*t);
            float sn = t * cs;
            float4 a, b;
            a.x = cs*wp0.x - sn*wq0.x;  a.y = cs*wp0.y - sn*wq0.y;
            a.z = cs*wp0.z - sn*wq0.z;  a.w = cs*wp0.w - sn*wq0.w;
            b.x = sn*wp0.x + cs*wq0.x;  b.y = sn*wp0.y + cs*wq0.y;
            b.z = sn*wp0.z + cs*wq0.z;  b.w = sn*wp0.w + cs*wq0.w;
            *(float4*)(Wp) = a;  *(float4*)(Wq) = b;
            a.x = cs*wp1.x - sn*wq1.x;  a.y = cs*wp1.y - sn*wq1.y;
            a.z = cs*wp1.z - sn*wq1.z;  a.w = cs*wp1.w - sn*wq1.w;
            b.x = sn*wp1.x + cs*wq1.x;  b.y = sn*wp1.y + cs*wq1.y;
            b.z = sn*wp1.z + cs*wq1.z;  b.w = sn*wp1.w + cs*wq1.w;
            *(float4*)(Wp + 4) = a;  *(float4*)(Wq + 4) = b;
        }
        __syncthreads();
      }
    }

    // column norms: group g handles cols 2g, 2g+1
    {
        int c0 = 2*g, c1 = 2*g + 1;
        const float* W0 = Wc + c0*64 + sl*8;
        const float* W1 = Wc + c1*64 + sl*8;
        float4 a0 = *(const float4*)(W0), a1 = *(const float4*)(W0 + 4);
        float4 b0 = *(const float4*)(W1), b1 = *(const float4*)(W1 + 4);
        float aa = a0.x*a0.x + a0.y*a0.y + a0.z*a0.z + a0.w*a0.w
                 + a1.x*a1.x + a1.y*a1.y + a1.z*a1.z + a1.w*a1.w;
        float bb = b0.x*b0.x + b0.y*b0.y + b0.z*b0.z + b0.w*b0.w
                 + b1.x*b1.x + b1.y*b1.y + b1.z*b1.z + b1.w*b1.w;
        aa += __shfl_xor(aa, 1, 8); bb += __shfl_xor(bb, 1, 8);
        aa += __shfl_xor(aa, 2, 8); bb += __shfl_xor(bb, 2, 8);
        aa += __shfl_xor(aa, 4, 8); bb += __shfl_xor(bb, 4, 8);
        if(sl == 0){ s2[c0] = aa; s2[c1] = bb; }
    }
    __syncthreads();
    if(tid == 0){
        float sm = 0.f;
        for(int c = 0; c < 64; ++c) sm = fmaxf(sm, s2[c]);
        smax_sh = sqrtf(sm);
    }
    __syncthreads();
    if(tid < 64){
        float s = sqrtf(s2[tid]);
        float v = vp[0];
        float tau = 0.4f / (1.f + expf(-v));     // sigmoid(v)*COEF_GAMMA
        float thr = tau * smax_sh;
        coef3[tid] = (s > thr && s > 1e-20f) ? (s - thr) / (s*s*s) : 0.f;
    }
    __syncthreads();

    // R1: T'[k][j] = coef3[k] * sum_r Wc[k][r] * Xsh[r][j]
    {
        int kk = tid >> 2;            // 0..63
        int j0 = (tid & 3) * 16;
        float acc[16];
        #pragma unroll
        for(int j = 0; j < 16; ++j) acc[j] = 0.f;
        for(int r = 0; r < 64; ++r){
            float wk = Wc[kk*64 + r];
            const float* xr = Xsh + r*64 + j0;
            float4 x0 = *(const float4*)(xr);
            float4 x1 = *(const float4*)(xr + 4);
            float4 x2 = *(const float4*)(xr + 8);
            float4 x3 = *(const float4*)(xr + 12);
            acc[0]+=wk*x0.x; acc[1]+=wk*x0.y; acc[2]+=wk*x0.z; acc[3]+=wk*x0.w;
            acc[4]+=wk*x1.x; acc[5]+=wk*x1.y; acc[6]+=wk*x1.z; acc[7]+=wk*x1.w;
            acc[8]+=wk*x2.x; acc[9]+=wk*x2.y; acc[10]+=wk*x2.z; acc[11]+=wk*x2.w;
            acc[12]+=wk*x3.x; acc[13]+=wk*x3.y; acc[14]+=wk*x3.z; acc[15]+=wk*x3.w;
        }
        float c3 = coef3[kk];
        float* tr = Tsh + kk*64 + j0;
        #pragma unroll
        for(int j = 0; j < 16; ++j) tr[j] = c3 * acc[j];
    }
    __syncthreads();

    // R2: Ltmp[i][j] = sum_k Wc[k][i] * T'[k][j]; write outputs
    {
        int i  = tid >> 2;            // 0..63
        int j0 = (tid & 3) * 16;
        float acc[16];
        #pragma unroll
        for(int j = 0; j < 16; ++j) acc[j] = 0.f;
        for(int kk = 0; kk < 64; ++kk){
            float wik = Wc[kk*64 + i];
            const float* tr = Tsh + kk*64 + j0;
            float4 t0 = *(const float4*)(tr);
            float4 t1 = *(const float4*)(tr + 4);
            float4 t2 = *(const float4*)(tr + 8);
            float4 t3 = *(const float4*)(tr + 12);
            acc[0]+=wik*t0.x; acc[1]+=wik*t0.y; acc[2]+=wik*t0.z; acc[3]+=wik*t0.w;
            acc[4]+=wik*t1.x; acc[5]+=wik*t1.y; acc[6]+=wik*t1.z; acc[7]+=wik*t1.w;
            acc[8]+=wik*t2.x; acc[9]+=wik*t2.y; acc[10]+=wik*t2.z; acc[11]+=wik*t2.w;
            acc[12]+=wik*t3.x; acc[13]+=wik*t3.y; acc[14]+=wik*t3.z; acc[15]+=wik*t3.w;
        }
        float neta = netap[0];
        int n0 = i*64 + j0;
        #pragma unroll
        for(int c = 0; c < 4; ++c){
            float4 th = *(const float4*)(thP + n0 + 4*c);
            float4 lt, pt;
            lt.x = acc[4*c+0]; lt.y = acc[4*c+1]; lt.z = acc[4*c+2]; lt.w = acc[4*c+3];
            float4 xs = *(const float4*)(Xsh + n0 + 4*c);
            pt.x = th.x + neta * (xs.x - th.x - lt.x);
            pt.y = th.y + neta * (xs.y - th.y - lt.y);
            pt.z = th.z + neta * (xs.z - th.z - lt.z);
            pt.w = th.w + neta * (xs.w - th.w - lt.w);
            *(float4*)(out + n0 + 4*c)      = lt;   // Ltmp
            *(float4*)(out + NN + n0 + 4*c) = pt;   // Ptmp
        }
    }
}

extern "C" void kernel_launch(void* const* d_in, const int* in_sizes, int n_in,
                              void* d_out, int out_size, void* d_ws, size_t ws_size,
                              hipStream_t stream){
    const float* inp  = (const float*)d_in[0];
    const float* L    = (const float*)d_in[1];
    const int*   mask = (const int*)  d_in[2];
    const float* D    = (const float*)d_in[3];
    const float* thP  = (const float*)d_in[4];
    const float* vS   = (const float*)d_in[5];
    const float* neta = (const float*)d_in[6];
    const float* l1   = (const float*)d_in[7];
    const float* l2   = (const float*)d_in[8];
    const float* rho  = (const float*)d_in[9];
    const float* S    = (const float*)d_in[10];
    float* wf = (float*)d_ws;
    float* out = (float*)d_out;
    const bool use_bf16 = (ws_size >= WS_NEED_BF16);
    unsigned short* Dh = (unsigned short*)((char*)d_ws + DH_OFF_BYTES);

    hipMemsetAsync(d_ws, 0, 64 * sizeof(float), stream);
    k_sts <<<16, 256, 0, stream>>>(S, wf);
    k_prep<<<16, 256, 0, stream>>>(inp, L, mask, D, thP, l1, l2, rho, wf);
    if(use_bf16){
        k_conv<<<8192, 256, 0, stream>>>(D, Dh);
        for(int it = 0; it < NITER; ++it){
            k_matvec_h<<<1024, 256, 0, stream>>>(Dh, l1, l2, wf);
            k_cgupd  <<<1, 1024, 0, stream>>>(wf);
        }
    } else {
        for(int it = 0; it < NITER; ++it){
            k_matvec_f<<<1024, 256, 0, stream>>>(D, l1, l2, wf);
            k_cgupd  <<<1, 1024, 0, stream>>>(wf);
        }
    }
    k_svt<<<1, 256, 0, stream>>>(thP, vS, neta, wf, out);
}

// Round 4
// 487.217 us; speedup vs baseline: 1.9463x; 1.0820x over previous
//
#include <hip/hip_runtime.h>
#include <hip/hip_bf16.h>

#define NN 4096
#define NITER 6
#define NSWEEP 6
#define WPAD 68   // padded column stride (floats) for Jacobi LDS: 68*4=272B, 16B-aligned, scatters banks

// workspace float layout
#define OFF_STS  64               // StS[4096]
#define OFF_QRHO (OFF_STS + NN)   // q_i + rho
#define OFF_DINV (OFF_QRHO + NN)  // 1/diag(A) approx (preconditioner only)
#define OFF_X    (OFF_DINV + NN)
#define OFF_R    (OFF_X + NN)
#define OFF_P    (OFF_R + NN)
#define OFF_Y    (OFF_P + NN)
// wf[0] = pTy accumulator, wf[1] = rz accumulator
#define DH_OFF_BYTES 131072              // bf16 copy of D at 128KB into ws
#define WS_NEED_BF16 (DH_OFF_BYTES + (size_t)NN * NN * 2)

typedef unsigned int uint;
__device__ inline float lo2f(uint w){ return __uint_as_float(w << 16); }
__device__ inline float hi2f(uint w){ return __uint_as_float(w & 0xffff0000u); }
__device__ inline uint f2b(float f){
    uint u = __float_as_uint(f);
    return (u + 0x7FFFu + ((u >> 16) & 1u)) >> 16;   // RNE
}

// ---------------- StS = S^T S (64x64) ----------------
__global__ void k_sts(const float* __restrict__ S, float* __restrict__ wf){
    int t = blockIdx.x * 256 + threadIdx.x;   // 4096 threads
    int r = t >> 6, c = t & 63;
    float acc = 0.f;
    for(int h = 0; h < 64; ++h)
        acc += S[h*64 + r] * S[h*64 + c];
    wf[OFF_STS + t] = acc;
}

// ---------------- prep: b, approx diag, CG init ----------------
__global__ void k_prep(const float* __restrict__ inp, const float* __restrict__ L,
                       const int*  __restrict__ mask,
                       const float* __restrict__ thP,
                       const float* __restrict__ l2p,
                       const float* __restrict__ rhop,
                       float* __restrict__ wf){
    int i = blockIdx.x * 256 + threadIdx.x;   // 4096 threads
    float rho = rhop[0], l2 = l2p[0];
    float q = (mask[i] != 0) ? 1.f : 0.f;
    float bi = rho * (L[i] - thP[i]) + q * inp[i];
    int u = i & 63;
    // preconditioner diag: drop tiny l1*D_ii term (|.|<~0.02 vs ~1.5) - exact A still used in matvec
    float diag = q + rho + l2 * wf[OFF_STS + u*64 + u];
    float dinv = 1.f / diag;
    wf[OFF_QRHO + i] = q + rho;
    wf[OFF_DINV + i] = dinv;
    wf[OFF_X + i]    = 0.f;
    wf[OFF_R + i]    = bi;
    float z = bi * dinv;
    wf[OFF_P + i]    = z;
    float part = bi * z;
    for(int m = 32; m >= 1; m >>= 1) part += __shfl_xor(part, m, 64);
    __shared__ float red[4];
    int wave = threadIdx.x >> 6, lane = threadIdx.x & 63;
    if(lane == 0) red[wave] = part;
    __syncthreads();
    if(threadIdx.x == 0) atomicAdd(&wf[1], red[0] + red[1] + red[2] + red[3]);
}

// ---------------- iter 0: y = A p from fp32 D, also emit bf16 Dh ----------------
__launch_bounds__(256)
__global__ void k_matvec_fc(const float* __restrict__ D, unsigned short* __restrict__ Dh,
                            const float* __restrict__ l1p, const float* __restrict__ l2p,
                            float* __restrict__ wf){
    __shared__ float psh[NN];
    __shared__ float red[4];
    const float* p    = wf + OFF_P;
    const float* qrho = wf + OFF_QRHO;
    const float* StS  = wf + OFF_STS;
    float* y          = wf + OFF_Y;
    int tid = threadIdx.x;
    const float4* p4 = (const float4*)p;
    float4* psh4 = (float4*)psh;
    for(int k = 0; k < 4; ++k) psh4[tid + k*256] = p4[tid + k*256];
    __syncthreads();

    float l1 = l1p[0], l2 = l2p[0];
    int wave = tid >> 6, lane = tid & 63;
    int row = blockIdx.x * 4 + wave;
    int h = row >> 6, u = row & 63;

    const float* Drow = D + (size_t)row * NN;
    unsigned short* Dhrow = Dh + (size_t)row * NN;
    float dacc = 0.f;
    for(int j = 0; j < 16; ++j){
        int c0 = j*256 + lane*4;
        float4 dv = *(const float4*)(Drow + c0);
        float4 pa = *(const float4*)(psh + c0);
        dacc += dv.x*pa.x + dv.y*pa.y + dv.z*pa.z + dv.w*pa.w;
        uint2 o;
        o.x = f2b(dv.x) | (f2b(dv.y) << 16);
        o.y = f2b(dv.z) | (f2b(dv.w) << 16);
        *(uint2*)(Dhrow + c0) = o;
    }
    float sacc = StS[u*64 + lane] * psh[h*64 + lane];
    float val = l1 * dacc + l2 * sacc;
    for(int m = 32; m >= 1; m >>= 1) val += __shfl_xor(val, m, 64);
    if(lane == 0){
        float yi = val + qrho[row] * psh[row];
        y[row] = yi;
        red[wave] = yi * psh[row];
    }
    __syncthreads();
    if(tid == 0) atomicAdd(&wf[0], red[0] + red[1] + red[2] + red[3]);
}

// ---------------- y = A p (bf16 D) ----------------
__launch_bounds__(256)
__global__ void k_matvec_h(const unsigned short* __restrict__ Dh,
                           const float* __restrict__ l1p, const float* __restrict__ l2p,
                           float* __restrict__ wf){
    __shared__ float psh[NN];
    __shared__ float red[4];
    const float* p    = wf + OFF_P;
    const float* qrho = wf + OFF_QRHO;
    const float* StS  = wf + OFF_STS;
    float* y          = wf + OFF_Y;
    int tid = threadIdx.x;
    const float4* p4 = (const float4*)p;
    float4* psh4 = (float4*)psh;
    for(int k = 0; k < 4; ++k) psh4[tid + k*256] = p4[tid + k*256];
    __syncthreads();

    float l1 = l1p[0], l2 = l2p[0];
    int wave = tid >> 6, lane = tid & 63;
    int row = blockIdx.x * 4 + wave;
    int h = row >> 6, u = row & 63;

    const unsigned short* Drow = Dh + (size_t)row * NN;
    float dacc = 0.f;
    for(int j = 0; j < 8; ++j){
        int c0 = j*512 + lane*8;
        uint4 dv = *(const uint4*)(Drow + c0);
        float4 pa = *(const float4*)(psh + c0);
        float4 pb = *(const float4*)(psh + c0 + 4);
        dacc += lo2f(dv.x)*pa.x + hi2f(dv.x)*pa.y
              + lo2f(dv.y)*pa.z + hi2f(dv.y)*pa.w
              + lo2f(dv.z)*pb.x + hi2f(dv.z)*pb.y
              + lo2f(dv.w)*pb.z + hi2f(dv.w)*pb.w;
    }
    float sacc = StS[u*64 + lane] * psh[h*64 + lane];
    float val = l1 * dacc + l2 * sacc;
    for(int m = 32; m >= 1; m >>= 1) val += __shfl_xor(val, m, 64);
    if(lane == 0){
        float yi = val + qrho[row] * psh[row];
        y[row] = yi;
        red[wave] = yi * psh[row];
    }
    __syncthreads();
    if(tid == 0) atomicAdd(&wf[0], red[0] + red[1] + red[2] + red[3]);
}

// ---------------- y = A p (fp32 D fallback, no conversion) ----------------
__launch_bounds__(256)
__global__ void k_matvec_f(const float* __restrict__ D,
                           const float* __restrict__ l1p, const float* __restrict__ l2p,
                           float* __restrict__ wf){
    __shared__ float psh[NN];
    __shared__ float red[4];
    const float* p    = wf + OFF_P;
    const float* qrho = wf + OFF_QRHO;
    const float* StS  = wf + OFF_STS;
    float* y          = wf + OFF_Y;
    int tid = threadIdx.x;
    const float4* p4 = (const float4*)p;
    float4* psh4 = (float4*)psh;
    for(int k = 0; k < 4; ++k) psh4[tid + k*256] = p4[tid + k*256];
    __syncthreads();

    float l1 = l1p[0], l2 = l2p[0];
    int wave = tid >> 6, lane = tid & 63;
    int row = blockIdx.x * 4 + wave;
    int h = row >> 6, u = row & 63;

    const float* Drow = D + (size_t)row * NN;
    float dacc = 0.f;
    for(int j = 0; j < 16; ++j){
        int c0 = j*256 + lane*4;
        float4 dv = *(const float4*)(Drow + c0);
        float4 pa = *(const float4*)(psh + c0);
        dacc += dv.x*pa.x + dv.y*pa.y + dv.z*pa.z + dv.w*pa.w;
    }
    float sacc = StS[u*64 + lane] * psh[h*64 + lane];
    float val = l1 * dacc + l2 * sacc;
    for(int m = 32; m >= 1; m >>= 1) val += __shfl_xor(val, m, 64);
    if(lane == 0){
        float yi = val + qrho[row] * psh[row];
        y[row] = yi;
        red[wave] = yi * psh[row];
    }
    __syncthreads();
    if(tid == 0) atomicAdd(&wf[0], red[0] + red[1] + red[2] + red[3]);
}

// ---------------- CG scalar/vector update (one block) ----------------
__launch_bounds__(1024)
__global__ void k_cgupd(float* __restrict__ wf){
    __shared__ float lds[16];
    int tid = threadIdx.x;
    float pTy = wf[0], rz = wf[1];
    float alpha = rz / pTy;
    float* x    = wf + OFF_X;
    float* r    = wf + OFF_R;
    float* p    = wf + OFF_P;
    const float* y    = wf + OFF_Y;
    const float* dinv = wf + OFF_DINV;

    float zi[4], pi[4];
    float part = 0.f;
    for(int k = 0; k < 4; ++k){
        int i = tid + k*1024;
        float pv = p[i]; pi[k] = pv;
        x[i] += alpha * pv;
        float rv = r[i] - alpha * y[i];
        r[i] = rv;
        float z = rv * dinv[i];
        zi[k] = z;
        part += rv * z;
    }
    for(int m = 32; m >= 1; m >>= 1) part += __shfl_xor(part, m, 64);
    int wave = tid >> 6, lane = tid & 63;
    if(lane == 0) lds[wave] = part;
    __syncthreads();
    float rznew = 0.f;
    for(int w = 0; w < 16; ++w) rznew += lds[w];
    float beta = rznew / rz;
    for(int k = 0; k < 4; ++k){
        int i = tid + k*1024;
        p[i] = zi[k] + beta * pi[k];
    }
    if(tid == 0){ wf[1] = rznew; wf[0] = 0.f; }
}

// ---------------- SVT: one-sided Jacobi, padded LDS, 2-wave sweeps ----------------
// After convergence W = U diag(s). Ltmp = W diag(relu(s-thr)/s^3) (W^T X).
__launch_bounds__(256)
__global__ void k_svt(const float* __restrict__ thP, const float* __restrict__ vp,
                      const float* __restrict__ netap,
                      const float* __restrict__ wf, float* __restrict__ out){
    __shared__ float Wc[64*WPAD];  // col-major, padded: Wc[c*WPAD+r]
    __shared__ float Xsh[NN];      // row-major: Xsh[r*64+j]
    __shared__ float Tsh[NN];      // T'[k*64+j]
    __shared__ float s2[64], coef3[64];
    __shared__ float smax_sh;
    int tid = threadIdx.x;
    const float* x = wf + OFF_X;

    // stage X = x + thP (row-major) and W = X (col-major padded)
    for(int k = 0; k < 16; ++k){
        int n = tid + k*256;
        int r = n >> 6, c = n & 63;
        float v = x[n] + thP[n];
        Xsh[n] = v;
        Wc[c*WPAD + r] = v;
    }
    __syncthreads();

    // sweeps: 128 active threads = 32 groups x 4 lanes, 16 floats/lane/column
    int g  = tid >> 2;      // pair group (0..31 for active)
    int sl = tid & 3;       // sub-lane: rows 16*sl .. 16*sl+15
    for(int sweep = 0; sweep < NSWEEP; ++sweep){
      for(int rnd = 0; rnd < 63; ++rnd){
        if(tid < 128){
            int p, q;
            if(g == 0){ p = 63; q = rnd; }
            else { p = (rnd + g) % 63; q = (rnd + 63 - g) % 63; }
            float* Wp = Wc + p*WPAD + sl*16;
            float* Wq = Wc + q*WPAD + sl*16;
            float4 wp0 = *(float4*)(Wp),     wp1 = *(float4*)(Wp + 4);
            float4 wp2 = *(float4*)(Wp + 8), wp3 = *(float4*)(Wp + 12);
            float4 wq0 = *(float4*)(Wq),     wq1 = *(float4*)(Wq + 4);
            float4 wq2 = *(float4*)(Wq + 8), wq3 = *(float4*)(Wq + 12);
            float aa = wp0.x*wp0.x + wp0.y*wp0.y + wp0.z*wp0.z + wp0.w*wp0.w
                     + wp1.x*wp1.x + wp1.y*wp1.y + wp1.z*wp1.z + wp1.w*wp1.w
                     + wp2.x*wp2.x + wp2.y*wp2.y + wp2.z*wp2.z + wp2.w*wp2.w
                     + wp3.x*wp3.x + wp3.y*wp3.y + wp3.z*wp3.z + wp3.w*wp3.w;
            float bb = wq0.x*wq0.x + wq0.y*wq0.y + wq0.z*wq0.z + wq0.w*wq0.w
                     + wq1.x*wq1.x + wq1.y*wq1.y + wq1.z*wq1.z + wq1.w*wq1.w
                     + wq2.x*wq2.x + wq2.y*wq2.y + wq2.z*wq2.z + wq2.w*wq2.w
                     + wq3.x*wq3.x + wq3.y*wq3.y + wq3.z*wq3.z + wq3.w*wq3.w;
            float cc = wp0.x*wq0.x + wp0.y*wq0.y + wp0.z*wq0.z + wp0.w*wq0.w
                     + wp1.x*wq1.x + wp1.y*wq1.y + wp1.z*wq1.z + wp1.w*wq1.w
                     + wp2.x*wq2.x + wp2.y*wq2.y + wp2.z*wq2.z + wp2.w*wq2.w
                     + wp3.x*wq3.x + wp3.y*wq3.y + wp3.z*wq3.z + wp3.w*wq3.w;
            aa += __shfl_xor(aa, 1, 4); bb += __shfl_xor(bb, 1, 4); cc += __shfl_xor(cc, 1, 4);
            aa += __shfl_xor(aa, 2, 4); bb += __shfl_xor(bb, 2, 4); cc += __shfl_xor(cc, 2, 4);
            if(fabsf(cc) > 1e-30f){
                float zeta = (bb - aa) / (2.f * cc);
                float t = copysignf(1.f / (fabsf(zeta) + sqrtf(1.f + zeta*zeta)), zeta);
                float cs = rsqrtf(1.f + t*t);
                float sn = t * cs;
                float4 a, b;
                a.x = cs*wp0.x - sn*wq0.x;  a.y = cs*wp0.y - sn*wq0.y;
                a.z = cs*wp0.z - sn*wq0.z;  a.w = cs*wp0.w - sn*wq0.w;
                b.x = sn*wp0.x + cs*wq0.x;  b.y = sn*wp0.y + cs*wq0.y;
                b.z = sn*wp0.z + cs*wq0.z;  b.w = sn*wp0.w + cs*wq0.w;
                *(float4*)(Wp) = a;  *(float4*)(Wq) = b;
                a.x = cs*wp1.x - sn*wq1.x;  a.y = cs*wp1.y - sn*wq1.y;
                a.z = cs*wp1.z - sn*wq1.z;  a.w = cs*wp1.w - sn*wq1.w;
                b.x = sn*wp1.x + cs*wq1.x;  b.y = sn*wp1.y + cs*wq1.y;
                b.z = sn*wp1.z + cs*wq1.z;  b.w = sn*wp1.w + cs*wq1.w;
                *(float4*)(Wp + 4) = a;  *(float4*)(Wq + 4) = b;
                a.x = cs*wp2.x - sn*wq2.x;  a.y = cs*wp2.y - sn*wq2.y;
                a.z = cs*wp2.z - sn*wq2.z;  a.w = cs*wp2.w - sn*wq2.w;
                b.x = sn*wp2.x + cs*wq2.x;  b.y = sn*wp2.y + cs*wq2.y;
                b.z = sn*wp2.z + cs*wq2.z;  b.w = sn*wp2.w + cs*wq2.w;
                *(float4*)(Wp + 8) = a;  *(float4*)(Wq + 8) = b;
                a.x = cs*wp3.x - sn*wq3.x;  a.y = cs*wp3.y - sn*wq3.y;
                a.z = cs*wp3.z - sn*wq3.z;  a.w = cs*wp3.w - sn*wq3.w;
                b.x = sn*wp3.x + cs*wq3.x;  b.y = sn*wp3.y + cs*wq3.y;
                b.z = sn*wp3.z + cs*wq3.z;  b.w = sn*wp3.w + cs*wq3.w;
                *(float4*)(Wp + 12) = a;  *(float4*)(Wq + 12) = b;
            }
        }
        __syncthreads();
      }
    }

    // column norms: 64 groups of 4 lanes, one column each
    {
        int c = tid >> 2;
        const float* W0 = Wc + c*WPAD + sl*16;
        float4 a0 = *(const float4*)(W0),     a1 = *(const float4*)(W0 + 4);
        float4 a2 = *(const float4*)(W0 + 8), a3 = *(const float4*)(W0 + 12);
        float aa = a0.x*a0.x + a0.y*a0.y + a0.z*a0.z + a0.w*a0.w
                 + a1.x*a1.x + a1.y*a1.y + a1.z*a1.z + a1.w*a1.w
                 + a2.x*a2.x + a2.y*a2.y + a2.z*a2.z + a2.w*a2.w
                 + a3.x*a3.x + a3.y*a3.y + a3.z*a3.z + a3.w*a3.w;
        aa += __shfl_xor(aa, 1, 4);
        aa += __shfl_xor(aa, 2, 4);
        if(sl == 0) s2[c] = aa;
    }
    __syncthreads();
    if(tid == 0){
        float sm = 0.f;
        for(int c = 0; c < 64; ++c) sm = fmaxf(sm, s2[c]);
        smax_sh = sqrtf(sm);
    }
    __syncthreads();
    if(tid < 64){
        float s = sqrtf(s2[tid]);
        float v = vp[0];
        float tau = 0.4f / (1.f + expf(-v));     // sigmoid(v)*COEF_GAMMA
        float thr = tau * smax_sh;
        coef3[tid] = (s > thr && s > 1e-20f) ? (s - thr) / (s*s*s) : 0.f;
    }
    __syncthreads();

    // R1: T'[k][j] = coef3[k] * sum_r Wc[k][r] * Xsh[r][j]
    {
        int kk = tid >> 2;            // 0..63
        int j0 = (tid & 3) * 16;
        float acc[16];
        #pragma unroll
        for(int j = 0; j < 16; ++j) acc[j] = 0.f;
        for(int r = 0; r < 64; ++r){
            float wk = Wc[kk*WPAD + r];
            const float* xr = Xsh + r*64 + j0;
            float4 x0 = *(const float4*)(xr);
            float4 x1 = *(const float4*)(xr + 4);
            float4 x2 = *(const float4*)(xr + 8);
            float4 x3 = *(const float4*)(xr + 12);
            acc[0]+=wk*x0.x; acc[1]+=wk*x0.y; acc[2]+=wk*x0.z; acc[3]+=wk*x0.w;
            acc[4]+=wk*x1.x; acc[5]+=wk*x1.y; acc[6]+=wk*x1.z; acc[7]+=wk*x1.w;
            acc[8]+=wk*x2.x; acc[9]+=wk*x2.y; acc[10]+=wk*x2.z; acc[11]+=wk*x2.w;
            acc[12]+=wk*x3.x; acc[13]+=wk*x3.y; acc[14]+=wk*x3.z; acc[15]+=wk*x3.w;
        }
        float c3 = coef3[kk];
        float* tr = Tsh + kk*64 + j0;
        #pragma unroll
        for(int j = 0; j < 16; ++j) tr[j] = c3 * acc[j];
    }
    __syncthreads();

    // R2: Ltmp[i][j] = sum_k Wc[k][i] * T'[k][j]; write outputs
    {
        int i  = tid >> 2;            // 0..63
        int j0 = (tid & 3) * 16;
        float acc[16];
        #pragma unroll
        for(int j = 0; j < 16; ++j) acc[j] = 0.f;
        for(int kk = 0; kk < 64; ++kk){
            float wik = Wc[kk*WPAD + i];
            const float* tr = Tsh + kk*64 + j0;
            float4 t0 = *(const float4*)(tr);
            float4 t1 = *(const float4*)(tr + 4);
            float4 t2 = *(const float4*)(tr + 8);
            float4 t3 = *(const float4*)(tr + 12);
            acc[0]+=wik*t0.x; acc[1]+=wik*t0.y; acc[2]+=wik*t0.z; acc[3]+=wik*t0.w;
            acc[4]+=wik*t1.x; acc[5]+=wik*t1.y; acc[6]+=wik*t1.z; acc[7]+=wik*t1.w;
            acc[8]+=wik*t2.x; acc[9]+=wik*t2.y; acc[10]+=wik*t2.z; acc[11]+=wik*t2.w;
            acc[12]+=wik*t3.x; acc[13]+=wik*t3.y; acc[14]+=wik*t3.z; acc[15]+=wik*t3.w;
        }
        float neta = netap[0];
        int n0 = i*64 + j0;
        #pragma unroll
        for(int c = 0; c < 4; ++c){
            float4 th = *(const float4*)(thP + n0 + 4*c);
            float4 lt, pt;
            lt.x = acc[4*c+0]; lt.y = acc[4*c+1]; lt.z = acc[4*c+2]; lt.w = acc[4*c+3];
            float4 xs = *(const float4*)(Xsh + n0 + 4*c);
            pt.x = th.x + neta * (xs.x - th.x - lt.x);
            pt.y = th.y + neta * (xs.y - th.y - lt.y);
            pt.z = th.z + neta * (xs.z - th.z - lt.z);
            pt.w = th.w + neta * (xs.w - th.w - lt.w);
            *(float4*)(out + n0 + 4*c)      = lt;   // Ltmp
            *(float4*)(out + NN + n0 + 4*c) = pt;   // Ptmp
        }
    }
}

extern "C" void kernel_launch(void* const* d_in, const int* in_sizes, int n_in,
                              void* d_out, int out_size, void* d_ws, size_t ws_size,
                              hipStream_t stream){
    const float* inp  = (const float*)d_in[0];
    const float* L    = (const float*)d_in[1];
    const int*   mask = (const int*)  d_in[2];
    const float* D    = (const float*)d_in[3];
    const float* thP  = (const float*)d_in[4];
    const float* vS   = (const float*)d_in[5];
    const float* neta = (const float*)d_in[6];
    const float* l1   = (const float*)d_in[7];
    const float* l2   = (const float*)d_in[8];
    const float* rho  = (const float*)d_in[9];
    const float* S    = (const float*)d_in[10];
    float* wf = (float*)d_ws;
    float* out = (float*)d_out;
    const bool use_bf16 = (ws_size >= WS_NEED_BF16);
    unsigned short* Dh = (unsigned short*)((char*)d_ws + DH_OFF_BYTES);

    hipMemsetAsync(d_ws, 0, 64 * sizeof(float), stream);
    k_sts <<<16, 256, 0, stream>>>(S, wf);
    k_prep<<<16, 256, 0, stream>>>(inp, L, mask, thP, l2, rho, wf);
    if(use_bf16){
        k_matvec_fc<<<1024, 256, 0, stream>>>(D, Dh, l1, l2, wf);  // iter 0 + conversion fused
        k_cgupd<<<1, 1024, 0, stream>>>(wf);
        for(int it = 1; it < NITER; ++it){
            k_matvec_h<<<1024, 256, 0, stream>>>(Dh, l1, l2, wf);
            k_cgupd  <<<1, 1024, 0, stream>>>(wf);
        }
    } else {
        for(int it = 0; it < NITER; ++it){
            k_matvec_f<<<1024, 256, 0, stream>>>(D, l1, l2, wf);
            k_cgupd  <<<1, 1024, 0, stream>>>(wf);
        }
    }
    k_svt<<<1, 256, 0, stream>>>(thP, vS, neta, wf, out);
}